// Round 2
// baseline (467.450 us; speedup 1.0000x reference)
//
#include <hip/hip_runtime.h>
#include <cstdint>
#include <cstddef>

#define ALPHA 0.2f
#define NEG_INF -1e30f

constexpr int B = 4, N = 512, IN_F = 256, E_F = 64, OUT_F = 256;

// ---------------------------------------------------------------------------
// K1: h = x @ W (4 rows/block, 512 blocks -> 2 blocks/CU), fused s_i/s_j.
//     Extra block (blockIdx.x == 512) computes w1a3 = W1 @ a3.
// ---------------------------------------------------------------------------
__global__ __launch_bounds__(256) void k_h(const float* __restrict__ x,
                                           const float* __restrict__ W,
                                           const float* __restrict__ W1,
                                           const float* __restrict__ a,
                                           float* __restrict__ h,
                                           float* __restrict__ s_i,
                                           float* __restrict__ s_j,
                                           float* __restrict__ w1a3) {
    int tid = threadIdx.x;
    if (blockIdx.x == (B * N) / 4) {
        // w1a3[e] = sum_o W1[e][o] * a[512+o]; 4 threads per e
        int e = tid >> 2, part = tid & 3;
        const float* row = W1 + (size_t)e * OUT_F + part * 64;
        const float* a3 = a + 2 * OUT_F + part * 64;
        float s = 0.f;
        #pragma unroll 8
        for (int o = 0; o < 64; ++o) s += row[o] * a3[o];
        s += __shfl_xor(s, 1);
        s += __shfl_xor(s, 2);
        if (part == 0) w1a3[e] = s;
        return;
    }
    int wv = tid >> 6, lane = tid & 63;
    int row = blockIdx.x * 4 + wv;     // each wave owns one row
    int c4 = lane * 4;                 // this lane's 4 output cols

    __shared__ float xs[4][IN_F];      // 4 KB
    *(float4*)&xs[wv][c4] = *(const float4*)&x[(size_t)row * IN_F + c4];
    __syncthreads();

    float4 acc = {0.f, 0.f, 0.f, 0.f};
    for (int k = 0; k < IN_F; ++k) {
        float4 w4 = *(const float4*)&W[(size_t)k * OUT_F + c4];
        float xv = xs[wv][k];          // broadcast
        acc.x = fmaf(xv, w4.x, acc.x);
        acc.y = fmaf(xv, w4.y, acc.y);
        acc.z = fmaf(xv, w4.z, acc.z);
        acc.w = fmaf(xv, w4.w, acc.w);
    }
    *(float4*)&h[(size_t)row * OUT_F + c4] = acc;

    float4 a1v = *(const float4*)&a[c4];
    float4 a2v = *(const float4*)&a[OUT_F + c4];
    float p1 = acc.x * a1v.x + acc.y * a1v.y + acc.z * a1v.z + acc.w * a1v.w;
    float p2 = acc.x * a2v.x + acc.y * a2v.y + acc.z * a2v.z + acc.w * a2v.w;
    #pragma unroll
    for (int off = 32; off; off >>= 1) {
        p1 += __shfl_xor(p1, off);
        p2 += __shfl_xor(p2, off);
    }
    if (lane == 0) { s_i[row] = p1; s_j[row] = p2; }
}

// ---------------------------------------------------------------------------
// K2: one block per (b,i). Lane l: j-slot = l>>2, e-quarter p = l&3.
//     4 independent float4 loads per j, NO shuffles in hot loop; partials to
//     LDS part[j][p] (word index == lane id -> conflict-free), one sync,
//     then leaky-relu + mask + softmax, write attention row.
// ---------------------------------------------------------------------------
__global__ __launch_bounds__(256) void k_att(const float* __restrict__ edge,
                                             const float* __restrict__ adj,
                                             const float* __restrict__ s_i,
                                             const float* __restrict__ s_j,
                                             const float* __restrict__ w1a3,
                                             float* __restrict__ att) {
    int bi = blockIdx.x;            // b*N + i
    int b = bi >> 9;
    int tid = threadIdx.x;
    int wv = tid >> 6, lane = tid & 63;
    int jl = lane >> 2;             // 0..15
    int p = lane & 3;               // e-quarter (16 floats)

    __shared__ float w1a3s[E_F];
    __shared__ float sjs[N];
    __shared__ float adjs[N];
    __shared__ float part[N][4];    // 8 KB
    __shared__ float redm[4], reds[4];

    if (tid < E_F) w1a3s[tid] = w1a3[tid];
    sjs[tid]        = s_j[b * N + tid];
    sjs[tid + 256]  = s_j[b * N + tid + 256];
    adjs[tid]       = adj[(size_t)bi * N + tid];
    adjs[tid + 256] = adj[(size_t)bi * N + tid + 256];
    float si = s_i[bi];
    __syncthreads();

    float4 wa = *(const float4*)&w1a3s[p * 16];
    float4 wb = *(const float4*)&w1a3s[p * 16 + 4];
    float4 wc = *(const float4*)&w1a3s[p * 16 + 8];
    float4 wd = *(const float4*)&w1a3s[p * 16 + 12];

    const float* ebase = edge + (size_t)bi * N * E_F;
    for (int it = 0; it < 8; ++it) {
        int j = it * 64 + wv * 16 + jl;
        const float4* ej = (const float4*)(ebase + (size_t)j * E_F + p * 16);
        float4 e0 = ej[0];
        float4 e1 = ej[1];
        float4 e2 = ej[2];
        float4 e3 = ej[3];
        float s = e0.x * wa.x + e0.y * wa.y + e0.z * wa.z + e0.w * wa.w;
        s = fmaf(e1.x, wb.x, s); s = fmaf(e1.y, wb.y, s);
        s = fmaf(e1.z, wb.z, s); s = fmaf(e1.w, wb.w, s);
        s = fmaf(e2.x, wc.x, s); s = fmaf(e2.y, wc.y, s);
        s = fmaf(e2.z, wc.z, s); s = fmaf(e2.w, wc.w, s);
        s = fmaf(e3.x, wd.x, s); s = fmaf(e3.y, wd.y, s);
        s = fmaf(e3.z, wd.z, s); s = fmaf(e3.w, wd.w, s);
        part[j][p] = s;
    }
    __syncthreads();

    // finish scores for j = tid and j = tid+256
    float v0 = si + sjs[tid] + part[tid][0] + part[tid][1] + part[tid][2] + part[tid][3];
    float v1 = si + sjs[tid + 256] + part[tid + 256][0] + part[tid + 256][1]
             + part[tid + 256][2] + part[tid + 256][3];
    v0 = v0 > 0.f ? v0 : ALPHA * v0;
    v1 = v1 > 0.f ? v1 : ALPHA * v1;
    v0 = (adjs[tid] > 0.f) ? v0 : NEG_INF;
    v1 = (adjs[tid + 256] > 0.f) ? v1 : NEG_INF;

    float m = fmaxf(v0, v1);
    #pragma unroll
    for (int off = 32; off; off >>= 1) m = fmaxf(m, __shfl_xor(m, off));
    if (lane == 0) redm[wv] = m;
    __syncthreads();
    m = fmaxf(fmaxf(redm[0], redm[1]), fmaxf(redm[2], redm[3]));

    float e0 = __expf(v0 - m);
    float e1 = __expf(v1 - m);
    float s = e0 + e1;
    #pragma unroll
    for (int off = 32; off; off >>= 1) s += __shfl_xor(s, off);
    if (lane == 0) reds[wv] = s;
    __syncthreads();
    s = reds[0] + reds[1] + reds[2] + reds[3];
    float inv = 1.f / s;

    att[(size_t)bi * N + tid]       = e0 * inv;
    att[(size_t)bi * N + tid + 256] = e1 * inv;
}

// ---------------------------------------------------------------------------
// K3: out = elu(att @ h). 4 rows/block (512 blocks), wave owns a row; h
//     streamed as float4 (1 KB per wave instr), att broadcast from LDS.
// ---------------------------------------------------------------------------
__global__ __launch_bounds__(256) void k_out(const float* __restrict__ att,
                                             const float* __restrict__ h,
                                             float* __restrict__ out) {
    int row0 = blockIdx.x * 4;
    int b = row0 >> 9;
    int tid = threadIdx.x;
    int wv = tid >> 6, lane = tid & 63;

    __shared__ float as_[4][N];     // 8 KB
    {
        const float* arow = att + (size_t)(row0 + wv) * N + lane * 8;
        *(float4*)&as_[wv][lane * 8]     = *(const float4*)arow;
        *(float4*)&as_[wv][lane * 8 + 4] = *(const float4*)(arow + 4);
    }
    __syncthreads();

    int c4 = lane * 4;
    const float* hb = h + (size_t)b * N * OUT_F;
    float4 acc = {0.f, 0.f, 0.f, 0.f};
    for (int k = 0; k < N; ++k) {
        float4 hv = *(const float4*)&hb[(size_t)k * OUT_F + c4];
        float av = as_[wv][k];      // broadcast
        acc.x = fmaf(av, hv.x, acc.x);
        acc.y = fmaf(av, hv.y, acc.y);
        acc.z = fmaf(av, hv.z, acc.z);
        acc.w = fmaf(av, hv.w, acc.w);
    }
    float4 o4;
    o4.x = acc.x > 0.f ? acc.x : (expf(acc.x) - 1.f);
    o4.y = acc.y > 0.f ? acc.y : (expf(acc.y) - 1.f);
    o4.z = acc.z > 0.f ? acc.z : (expf(acc.z) - 1.f);
    o4.w = acc.w > 0.f ? acc.w : (expf(acc.w) - 1.f);
    *(float4*)&out[(size_t)(row0 + wv) * OUT_F + c4] = o4;
}

// ---------------------------------------------------------------------------
extern "C" void kernel_launch(void* const* d_in, const int* in_sizes, int n_in,
                              void* d_out, int out_size, void* d_ws, size_t ws_size,
                              hipStream_t stream) {
    const float* x    = (const float*)d_in[0];   // (4,512,256)
    const float* edge = (const float*)d_in[1];   // (4,512,512,64)
    const float* adj  = (const float*)d_in[2];   // (4,512,512)
    const float* W    = (const float*)d_in[3];   // (256,256)
    const float* W1   = (const float*)d_in[4];   // (64,256)
    const float* a    = (const float*)d_in[5];   // (768,1)
    float* out = (float*)d_out;                  // (4,512,256)

    float* ws = (float*)d_ws;
    float* h_buf    = ws;                              // 524288 floats
    float* att_buf  = h_buf + (size_t)B * N * OUT_F;   // 1048576 floats
    float* si_buf   = att_buf + (size_t)B * N * N;     // 2048
    float* sj_buf   = si_buf + B * N;                  // 2048
    float* w1a3_buf = sj_buf + B * N;                  // 64

    k_h<<<(B * N) / 4 + 1, 256, 0, stream>>>(x, W, W1, a, h_buf, si_buf, sj_buf, w1a3_buf);
    k_att<<<B * N, 256, 0, stream>>>(edge, adj, si_buf, sj_buf, w1a3_buf, att_buf);
    k_out<<<(B * N) / 4, 256, 0, stream>>>(att_buf, h_buf, out);
}

// Round 3
// 409.459 us; speedup vs baseline: 1.1416x; 1.1416x over previous
//
#include <hip/hip_runtime.h>
#include <cstdint>
#include <cstddef>

#define ALPHA 0.2f
#define NEG_INF -1e30f

constexpr int B = 4, N = 512, IN_F = 256, E_F = 64, OUT_F = 256;

// ---------------------------------------------------------------------------
// K1: h = x @ W (4 rows/block, 512 blocks), fused s_i/s_j.
//     Extra block (blockIdx.x == 512) computes w1a3 = W1 @ a3.
// ---------------------------------------------------------------------------
__global__ __launch_bounds__(256) void k_h(const float* __restrict__ x,
                                           const float* __restrict__ W,
                                           const float* __restrict__ W1,
                                           const float* __restrict__ a,
                                           float* __restrict__ h,
                                           float* __restrict__ s_i,
                                           float* __restrict__ s_j,
                                           float* __restrict__ w1a3) {
    int tid = threadIdx.x;
    if (blockIdx.x == (B * N) / 4) {
        int e = tid >> 2, part = tid & 3;
        const float* row = W1 + (size_t)e * OUT_F + part * 64;
        const float* a3 = a + 2 * OUT_F + part * 64;
        float s = 0.f;
        #pragma unroll 8
        for (int o = 0; o < 64; ++o) s += row[o] * a3[o];
        s += __shfl_xor(s, 1);
        s += __shfl_xor(s, 2);
        if (part == 0) w1a3[e] = s;
        return;
    }
    int wv = tid >> 6, lane = tid & 63;
    int row = blockIdx.x * 4 + wv;     // each wave owns one row
    int c4 = lane * 4;

    __shared__ float xs[4][IN_F];
    *(float4*)&xs[wv][c4] = *(const float4*)&x[(size_t)row * IN_F + c4];
    __syncthreads();

    float4 acc = {0.f, 0.f, 0.f, 0.f};
    for (int k = 0; k < IN_F; ++k) {
        float4 w4 = *(const float4*)&W[(size_t)k * OUT_F + c4];
        float xv = xs[wv][k];
        acc.x = fmaf(xv, w4.x, acc.x);
        acc.y = fmaf(xv, w4.y, acc.y);
        acc.z = fmaf(xv, w4.z, acc.z);
        acc.w = fmaf(xv, w4.w, acc.w);
    }
    *(float4*)&h[(size_t)row * OUT_F + c4] = acc;

    float4 a1v = *(const float4*)&a[c4];
    float4 a2v = *(const float4*)&a[OUT_F + c4];
    float p1 = acc.x * a1v.x + acc.y * a1v.y + acc.z * a1v.z + acc.w * a1v.w;
    float p2 = acc.x * a2v.x + acc.y * a2v.y + acc.z * a2v.z + acc.w * a2v.w;
    #pragma unroll
    for (int off = 32; off; off >>= 1) {
        p1 += __shfl_xor(p1, off);
        p2 += __shfl_xor(p2, off);
    }
    if (lane == 0) { s_i[row] = p1; s_j[row] = p2; }
}

// ---------------------------------------------------------------------------
// K2 (fused att + out): one block per (b,i), 256 threads.
//   Phase A: s_e dots with FULLY CONTIGUOUS edge loads — per wave-load, lane l
//     reads 16B at byte offset l*16 of a 1KB window (4 consecutive j rows).
//     Lane (jg=l>>4, col=l&15) -> j = jw + i*4 + jg, e-slice col*4..col*4+4.
//     Partials to part[j][col] (pad 17 -> <=3-way banked, ~free).
//   Softmax in LDS, att row written into sjs (reused).
//   Phase B: h_prime = att_row @ h[b]; wave wv owns k in [wv*128,+128), lane
//     owns cols c4..c4+3 (1KB contiguous per wave-instr, h is L2-resident).
//     Partial accs reduced via part[] (reused as flat [4][256]). Fused elu.
// ---------------------------------------------------------------------------
__global__ __launch_bounds__(256) void k_att_out(const float* __restrict__ edge,
                                                 const float* __restrict__ adj,
                                                 const float* __restrict__ s_i,
                                                 const float* __restrict__ s_j,
                                                 const float* __restrict__ w1a3,
                                                 const float* __restrict__ h,
                                                 float* __restrict__ out) {
    int bi = blockIdx.x;            // b*N + i
    int b = bi >> 9;
    int tid = threadIdx.x;
    int wv = tid >> 6, lane = tid & 63;

    __shared__ __align__(16) float part[N][17];   // 34816 B, reused in phase B
    __shared__ float sjs[N];                      // reused as att row
    __shared__ float adjs[N];
    __shared__ __align__(16) float w1a3s[E_F];
    __shared__ float redm[4], reds[4];

    if (tid < E_F) w1a3s[tid] = w1a3[tid];
    sjs[tid]        = s_j[b * N + tid];
    sjs[tid + 256]  = s_j[b * N + tid + 256];
    adjs[tid]       = adj[(size_t)bi * N + tid];
    adjs[tid + 256] = adj[(size_t)bi * N + tid + 256];
    float si = s_i[bi];
    __syncthreads();

    int col = lane & 15;            // e-slice (4 floats)
    int jg  = lane >> 4;            // 0..3 within 4-j group
    float4 w4 = *(const float4*)&w1a3s[col * 4];
    const float* ebase = edge + (size_t)bi * N * E_F;

    #pragma unroll
    for (int it = 0; it < 8; ++it) {
        int jw = it * 64 + wv * 16;
        #pragma unroll
        for (int i = 0; i < 4; ++i) {
            int j = jw + i * 4 + jg;
            float4 ev = *(const float4*)(ebase + (size_t)j * E_F + col * 4);
            part[j][col] = ev.x * w4.x + ev.y * w4.y + ev.z * w4.z + ev.w * w4.w;
        }
    }
    __syncthreads();

    // finish scores for j = tid and j = tid + 256
    float v0 = si + sjs[tid];
    float v1 = si + sjs[tid + 256];
    #pragma unroll
    for (int c = 0; c < 16; ++c) {
        v0 += part[tid][c];
        v1 += part[tid + 256][c];
    }
    v0 = v0 > 0.f ? v0 : ALPHA * v0;
    v1 = v1 > 0.f ? v1 : ALPHA * v1;
    v0 = (adjs[tid] > 0.f) ? v0 : NEG_INF;
    v1 = (adjs[tid + 256] > 0.f) ? v1 : NEG_INF;

    float m = fmaxf(v0, v1);
    #pragma unroll
    for (int off = 32; off; off >>= 1) m = fmaxf(m, __shfl_xor(m, off));
    if (lane == 0) redm[wv] = m;
    __syncthreads();
    m = fmaxf(fmaxf(redm[0], redm[1]), fmaxf(redm[2], redm[3]));

    float e0 = __expf(v0 - m);
    float e1 = __expf(v1 - m);
    float s = e0 + e1;
    #pragma unroll
    for (int off = 32; off; off >>= 1) s += __shfl_xor(s, off);
    if (lane == 0) reds[wv] = s;
    __syncthreads();
    s = reds[0] + reds[1] + reds[2] + reds[3];
    float inv = 1.f / s;

    // att row into sjs (all sjs reads are complete: two syncs above)
    sjs[tid]       = e0 * inv;
    sjs[tid + 256] = e1 * inv;
    __syncthreads();

    // Phase B: out[bi][:] = elu(att_row @ h[b])
    const float* hb = h + (size_t)b * N * OUT_F;
    int c4 = lane * 4;
    float4 acc = {0.f, 0.f, 0.f, 0.f};
    int k0 = wv * 128;
    for (int k = k0; k < k0 + 128; ++k) {
        float av = sjs[k];
        float4 hv = *(const float4*)&hb[(size_t)k * OUT_F + c4];
        acc.x = fmaf(av, hv.x, acc.x);
        acc.y = fmaf(av, hv.y, acc.y);
        acc.z = fmaf(av, hv.z, acc.z);
        acc.w = fmaf(av, hv.w, acc.w);
    }
    float* flat = &part[0][0];          // reuse as pacc[4][256]
    ((float4*)(flat + wv * 256))[lane] = acc;
    __syncthreads();
    float r = flat[tid] + flat[256 + tid] + flat[512 + tid] + flat[768 + tid];
    out[(size_t)bi * OUT_F + tid] = r > 0.f ? r : (expf(r) - 1.f);
}

// ---------------------------------------------------------------------------
extern "C" void kernel_launch(void* const* d_in, const int* in_sizes, int n_in,
                              void* d_out, int out_size, void* d_ws, size_t ws_size,
                              hipStream_t stream) {
    const float* x    = (const float*)d_in[0];   // (4,512,256)
    const float* edge = (const float*)d_in[1];   // (4,512,512,64)
    const float* adj  = (const float*)d_in[2];   // (4,512,512)
    const float* W    = (const float*)d_in[3];   // (256,256)
    const float* W1   = (const float*)d_in[4];   // (64,256)
    const float* a    = (const float*)d_in[5];   // (768,1)
    float* out = (float*)d_out;                  // (4,512,256)

    float* ws = (float*)d_ws;
    float* h_buf    = ws;                              // 524288 floats
    float* si_buf   = h_buf + (size_t)B * N * OUT_F;   // 2048
    float* sj_buf   = si_buf + B * N;                  // 2048
    float* w1a3_buf = sj_buf + B * N;                  // 64

    k_h<<<(B * N) / 4 + 1, 256, 0, stream>>>(x, W, W1, a, h_buf, si_buf, sj_buf, w1a3_buf);
    k_att_out<<<B * N, 256, 0, stream>>>(edge, adj, si_buf, sj_buf, w1a3_buf, h_buf, out);
}